// Round 2
// baseline (357.815 us; speedup 1.0000x reference)
//
#include <hip/hip_runtime.h>

#define NF 32  // IN_FEATS == OUT_FEATS == 32
#define SCAN_BLOCK 256
#define ELEMS_PER_BLOCK 1024  // SCAN_BLOCK * 4

// Stage 1: in-degree histogram over dst (self-loop handled separately).
__global__ void deg_kernel(const int* __restrict__ dst, int* __restrict__ deg, int n_edges) {
    int i = blockIdx.x * blockDim.x + threadIdx.x;
    if (i < n_edges) atomicAdd(&deg[dst[i]], 1);
}

// Scan pass A: per-block (1024-elem) exclusive scan of deg -> rowstart (partial), block totals -> bsum.
__global__ void scanA_kernel(const int* __restrict__ deg, int* __restrict__ rowstart,
                             int* __restrict__ bsum, int n) {
    __shared__ int lds[SCAN_BLOCK];
    int t = threadIdx.x;
    int base = blockIdx.x * ELEMS_PER_BLOCK + t * 4;
    int v[4];
#pragma unroll
    for (int k = 0; k < 4; k++) v[k] = (base + k < n) ? deg[base + k] : 0;
    int tsum = v[0] + v[1] + v[2] + v[3];
    lds[t] = tsum;
    __syncthreads();
    for (int off = 1; off < SCAN_BLOCK; off <<= 1) {
        int x = (t >= off) ? lds[t - off] : 0;
        __syncthreads();
        lds[t] += x;
        __syncthreads();
    }
    int ex = lds[t] - tsum;  // exclusive prefix for this thread's 4 elems
    if (t == SCAN_BLOCK - 1) bsum[blockIdx.x] = lds[t];
#pragma unroll
    for (int k = 0; k < 4; k++) {
        if (base + k < n) rowstart[base + k] = ex;
        ex += v[k];
    }
}

// Scan pass B: exclusive scan of block totals (nb <= 1024) in one block.
__global__ void scanB_kernel(int* __restrict__ bsum, int nb) {
    __shared__ int lds[1024];
    int t = threadIdx.x;
    int v = (t < nb) ? bsum[t] : 0;
    lds[t] = v;
    __syncthreads();
    for (int off = 1; off < 1024; off <<= 1) {
        int x = (t >= off) ? lds[t - off] : 0;
        __syncthreads();
        lds[t] += x;
        __syncthreads();
    }
    if (t < nb) bsum[t] = lds[t] - v;  // exclusive
}

// Scan pass C: add block offsets; also initialize cursor = rowstart.
__global__ void scanC_kernel(int* __restrict__ rowstart, const int* __restrict__ bsum,
                             int* __restrict__ cursor, int n) {
    int i = blockIdx.x * blockDim.x + threadIdx.x;
    if (i < n) {
        int v = rowstart[i] + bsum[i >> 10];
        rowstart[i] = v;
        cursor[i] = v;
    }
}

// CSR build: bucket-place each edge's src into its dst segment.
__global__ void csr_kernel(const int* __restrict__ src, const int* __restrict__ dst,
                           int* __restrict__ cursor, int* __restrict__ esrc, int n_edges) {
    int e = blockIdx.x * blockDim.x + threadIdx.x;
    if (e < n_edges) {
        int pos = atomicAdd(&cursor[dst[e]], 1);
        esrc[pos] = src[e];
    }
}

// Projection: h[n] = (x[n] * rsqrt(deg+1)) @ W^T ; also writes isd.
__global__ void proj_kernel(const float* __restrict__ x, const float* __restrict__ W,
                            const int* __restrict__ deg, float* __restrict__ isd,
                            float* __restrict__ h, int n_nodes) {
    __shared__ float sWt[NF * NF];
    int t = threadIdx.x;
    for (int k = t; k < NF * NF; k += 256) sWt[k] = W[(k & 31) * NF + (k >> 5)];
    __syncthreads();
    int node = blockIdx.x * 8 + (t >> 5);
    int o = t & 31;
    if (node < n_nodes) {
        float s = rsqrtf((float)(deg[node] + 1));  // +1 self-loop; >=1 always
        if (o == 0) isd[node] = s;
        const float* xr = x + (size_t)node * NF;
        float acc = 0.f;
#pragma unroll
        for (int i = 0; i < NF; i++) acc = fmaf(xr[i], sWt[i * NF + o], acc);
        h[node * NF + o] = acc * s;
    }
}

// Gather-aggregate + finalize: per node, acc = h[n] + sum_{e in seg(n)} h[esrc[e]];
// out = relu(acc * isd + bias). Half-wave (32 lanes = 32 feats) per node.
__global__ void gather_kernel(const int* __restrict__ rowstart, const int* __restrict__ deg,
                              const int* __restrict__ esrc, const float* __restrict__ h,
                              const float* __restrict__ isd, const float* __restrict__ bias,
                              float* __restrict__ out, int n_nodes) {
    int t = threadIdx.x;
    int node = blockIdx.x * 8 + (t >> 5);
    int o = t & 31;
    if (node >= n_nodes) return;
    int start = rowstart[node];
    int cnt = deg[node];
    float acc = h[node * NF + o];  // self-loop
    for (int base = 0; base < cnt; base += 32) {
        int j = base + o;
        int sv = (j < cnt) ? esrc[start + j] : 0;  // coalesced 32-wide index load
        int m = min(cnt - base, 32);
        for (int k = 0; k < m; k++) {
            int s = __shfl(sv, k, 32);  // broadcast edge k's src within 32-lane group
            acc += h[s * NF + o];       // coalesced 128B row gather
        }
    }
    float v = fmaf(acc, isd[node], bias[o]);
    out[node * NF + o] = fmaxf(v, 0.f);
}

extern "C" void kernel_launch(void* const* d_in, const int* in_sizes, int n_in,
                              void* d_out, int out_size, void* d_ws, size_t ws_size,
                              hipStream_t stream) {
    const float* feature = (const float*)d_in[0];
    const int*   src     = (const int*)d_in[1];
    const int*   dst     = (const int*)d_in[2];
    const float* W       = (const float*)d_in[3];
    const float* bias    = (const float*)d_in[4];
    float* out = (float*)d_out;

    int n_nodes = in_sizes[0] / NF;
    int n_edges = in_sizes[1];

    char* ws = (char*)d_ws;
    size_t off = 0;
    int* deg = (int*)(ws + off);       off += ((size_t)n_nodes * 4 + 255) & ~(size_t)255;
    int* rowstart = (int*)(ws + off);  off += ((size_t)n_nodes * 4 + 255) & ~(size_t)255;
    int* cursor = (int*)(ws + off);    off += ((size_t)n_nodes * 4 + 255) & ~(size_t)255;
    float* isd = (float*)(ws + off);   off += ((size_t)n_nodes * 4 + 255) & ~(size_t)255;
    int* bsum = (int*)(ws + off);      off += 4096;
    int* esrc = (int*)(ws + off);      off += ((size_t)n_edges * 4 + 255) & ~(size_t)255;
    float* h = (float*)(ws + off);

    hipMemsetAsync(deg, 0, (size_t)n_nodes * 4, stream);

    deg_kernel<<<(n_edges + 255) / 256, 256, 0, stream>>>(dst, deg, n_edges);

    int nb = (n_nodes + ELEMS_PER_BLOCK - 1) / ELEMS_PER_BLOCK;
    scanA_kernel<<<nb, SCAN_BLOCK, 0, stream>>>(deg, rowstart, bsum, n_nodes);
    scanB_kernel<<<1, 1024, 0, stream>>>(bsum, nb);
    scanC_kernel<<<(n_nodes + 255) / 256, 256, 0, stream>>>(rowstart, bsum, cursor, n_nodes);

    csr_kernel<<<(n_edges + 255) / 256, 256, 0, stream>>>(src, dst, cursor, esrc, n_edges);

    proj_kernel<<<(n_nodes + 7) / 8, 256, 0, stream>>>(feature, W, deg, isd, h, n_nodes);

    gather_kernel<<<(n_nodes + 7) / 8, 256, 0, stream>>>(rowstart, deg, esrc, h, isd, bias,
                                                         out, n_nodes);
}